// Round 1
// baseline (232.524 us; speedup 1.0000x reference)
//
#include <hip/hip_runtime.h>
#include <hip/hip_bf16.h>

typedef short v8s __attribute__((ext_vector_type(8)));
typedef float v4f __attribute__((ext_vector_type(4)));

#define B_ 8
#define N_ 8192
#define F_ 128
#define K_ 512
#define M_ (B_ * N_)   // 65536 rows
#define PSTR 136       // P LDS stride (elements); 272B rows, 16B-aligned, breaks pow2 banks

__device__ __forceinline__ short f2bf(float f) {
    union { float f; unsigned u; } v; v.f = f;
    unsigned u = v.u;
    u = (u + 0x7FFFu + ((u >> 16) & 1u)) >> 16;  // RNE
    return (short)u;
}
__device__ __forceinline__ float bf2f(short s) {
    union { float f; unsigned u; } v;
    v.u = ((unsigned)(unsigned short)s) << 16;
    return v.f;
}

// Convert centers to bf16 in two layouts + squared norms (from bf16-rounded values).
__global__ void prep_kernel(const float* __restrict__ centers,
                            short* __restrict__ Cb, short* __restrict__ CT,
                            float* __restrict__ csq) {
    int c = blockIdx.x;    // 512 clusters
    int f = threadIdx.x;   // 128 features
    float v = centers[c * F_ + f];
    short b = f2bf(v);
    float vb = bf2f(b);
    Cb[c * F_ + f] = b;        // [cluster][f]   (stage-1 B reads: contiguous in f)
    CT[f * K_ + c] = b;        // [f][cluster]   (stage-2 B reads: contiguous in cluster)
    float s = vb * vb;
    #pragma unroll
    for (int off = 1; off < 64; off <<= 1) s += __shfl_xor(s, off);
    __shared__ float part[2];
    if ((f & 63) == 0) part[f >> 6] = s;
    __syncthreads();
    if (f == 0) csq[c] = part[0] + part[1];
}

// One wave = 16 rows. Full K=512 per row: cross-MFMA -> d -> p=exp(-d) -> LDS
// (C-layout -> A-layout) -> PV-MFMA. No max-subtraction needed: -d <= 0 so
// exp in (0,1]; d~16 keeps values ~1e-7, far from fp32 underflow.
__global__ __launch_bounds__(256) void cluster_kernel(
        const float* __restrict__ x, const short* __restrict__ Cb,
        const short* __restrict__ CT, const float* __restrict__ csq,
        float* __restrict__ out) {
    __shared__ __align__(16) short Plds[4][16 * PSTR];
    const int wave = threadIdx.x >> 6;
    const int lane = threadIdx.x & 63;
    const int q = lane >> 4;
    const int lr = lane & 15;
    const int row0 = blockIdx.x * 64 + wave * 16;

    // A fragments: x rows in bf16. A[m=lane&15][k=(lane>>4)*8+j], k-step 32.
    v8s Ax[4];
    float xs = 0.f;
    const float* xrow = x + (size_t)(row0 + lr) * F_;
    #pragma unroll
    for (int ks = 0; ks < 4; ++ks) {
        const float4* p = (const float4*)(xrow + ks * 32 + q * 8);
        float4 a = p[0], b = p[1];
        float vv[8] = {a.x, a.y, a.z, a.w, b.x, b.y, b.z, b.w};
        v8s fr;
        #pragma unroll
        for (int j = 0; j < 8; ++j) {
            short bb = f2bf(vv[j]);
            fr[j] = bb;
            float r = bf2f(bb);
            xs += r * r;   // ||x~||^2 from bf16-rounded values (consistent with MFMA cross)
        }
        Ax[ks] = fr;
    }
    // xs currently: lane(q,lr) holds partial of row lr over its 32 k's -> reduce over q
    xs += __shfl_xor(xs, 16);
    xs += __shfl_xor(xs, 32);
    // Fetch ||x||^2 for this lane's C-rows (row = q*4+r); source lane q*4+r has lr==q*4+r
    float xsq_r[4];
    #pragma unroll
    for (int r = 0; r < 4; ++r) xsq_r[r] = __shfl(xs, q * 4 + r);

    short* Pl = Plds[wave];
    v4f Of[8];
    #pragma unroll
    for (int i = 0; i < 8; ++i) Of[i] = (v4f){0.f, 0.f, 0.f, 0.f};
    float lpart[4] = {0.f, 0.f, 0.f, 0.f};

    for (int kc = 0; kc < 4; ++kc) {
        // ---- stage 1: scores for 128-cluster chunk ----
        #pragma unroll
        for (int blk = 0; blk < 8; ++blk) {
            const int cl = kc * 128 + blk * 16 + lr;
            v4f acc = (v4f){0.f, 0.f, 0.f, 0.f};
            const short* bbase = Cb + cl * F_ + q * 8;   // B[n=cluster][k=f]: 16B contiguous
            #pragma unroll
            for (int ks = 0; ks < 4; ++ks) {
                v8s bf = *(const v8s*)(bbase + ks * 32);
                acc = __builtin_amdgcn_mfma_f32_16x16x32_bf16(Ax[ks], bf, acc, 0, 0, 0);
            }
            const float cq = csq[cl];
            // C/D layout: col=lane&15 (cluster), row=(lane>>4)*4+reg (x-row)
            #pragma unroll
            for (int r = 0; r < 4; ++r) {
                float d2 = xsq_r[r] + cq - 2.0f * acc[r];
                float d = sqrtf(fmaxf(d2, 0.f));
                float pp = __expf(-d);
                short pb = f2bf(pp);
                lpart[r] += bf2f(pb);   // denominator from SAME rounded p -> errors cancel
                Pl[(q * 4 + r) * PSTR + blk * 16 + lr] = pb;
            }
        }
        // ---- stage 2: O += P * C_chunk (wave-private LDS, DS in-order per wave) ----
        #pragma unroll
        for (int ks2 = 0; ks2 < 4; ++ks2) {
            v8s pf = *(const v8s*)(Pl + lr * PSTR + ks2 * 32 + q * 8);  // A[m=lr][k]
            #pragma unroll
            for (int fblk = 0; fblk < 8; ++fblk) {
                const int f = fblk * 16 + lr;
                v8s bf = *(const v8s*)(CT + (size_t)f * K_ + kc * 128 + ks2 * 32 + q * 8);
                Of[fblk] = __builtin_amdgcn_mfma_f32_16x16x32_bf16(pf, bf, Of[fblk], 0, 0, 0);
            }
        }
    }

    // Row sums: lpart[r] holds cols {lr+16*blk} of row q*4+r -> reduce over lr nibble
    #pragma unroll
    for (int r = 0; r < 4; ++r) {
        float s = lpart[r];
        s += __shfl_xor(s, 1);
        s += __shfl_xor(s, 2);
        s += __shfl_xor(s, 4);
        s += __shfl_xor(s, 8);
        lpart[r] = 1.0f / s;
    }
    #pragma unroll
    for (int fblk = 0; fblk < 8; ++fblk) {
        #pragma unroll
        for (int r = 0; r < 4; ++r) {
            const int row = row0 + q * 4 + r;
            out[(size_t)row * F_ + fblk * 16 + lr] = Of[fblk][r] * lpart[r];
        }
    }
}

extern "C" void kernel_launch(void* const* d_in, const int* in_sizes, int n_in,
                              void* d_out, int out_size, void* d_ws, size_t ws_size,
                              hipStream_t stream) {
    const float* x       = (const float*)d_in[0];   // [8,8192,128] fp32
    const float* centers = (const float*)d_in[1];   // [512,128] fp32
    float* out = (float*)d_out;                     // [8,8192,128] fp32
    char* ws = (char*)d_ws;
    short* Cb  = (short*)ws;                 // 512*128*2  = 131072 B
    short* CT  = (short*)(ws + 131072);      // 128*512*2  = 131072 B
    float* csq = (float*)(ws + 262144);      // 512*4      = 2048 B
    prep_kernel<<<K_, F_, 0, stream>>>(centers, Cb, CT, csq);
    cluster_kernel<<<M_ / 64, 256, 0, stream>>>(x, Cb, CT, csq, out);
}

// Round 2
// 143.520 us; speedup vs baseline: 1.6202x; 1.6202x over previous
//
#include <hip/hip_runtime.h>
#include <hip/hip_bf16.h>

typedef short v8s __attribute__((ext_vector_type(8)));
typedef float v4f __attribute__((ext_vector_type(4)));

#define B_ 8
#define N_ 8192
#define F_ 128
#define K_ 512
#define M_ (B_ * N_)   // 65536 rows
#define PSTR 136       // P LDS stride: 272B rows = 17*16B -> b128-aligned, breaks pow2 banks

__device__ __forceinline__ short f2bf(float f) {
    union { float f; unsigned u; } v; v.f = f;
    unsigned u = v.u;
    u = (u + 0x7FFFu + ((u >> 16) & 1u)) >> 16;  // RNE
    return (short)u;
}
__device__ __forceinline__ float bf2f(short s) {
    union { float f; unsigned u; } v;
    v.u = ((unsigned)(unsigned short)s) << 16;
    return v.f;
}

// One wave per cluster: bf16 convert (both layouts) + squared norm of rounded values.
__global__ void prep_kernel(const float* __restrict__ centers,
                            short* __restrict__ Cb, short* __restrict__ CT,
                            float* __restrict__ csq) {
    const int wave = threadIdx.x >> 6;
    const int lane = threadIdx.x & 63;
    const int c = blockIdx.x * 4 + wave;
    float s = 0.f;
    #pragma unroll
    for (int h = 0; h < 2; ++h) {
        const int f = h * 64 + lane;
        float v = centers[c * F_ + f];
        short b = f2bf(v);
        Cb[c * F_ + f] = b;        // [cluster][f]  stage-1 B
        CT[f * K_ + c] = b;        // [f][cluster]  stage-2 B
        float vb = bf2f(b);
        s += vb * vb;
    }
    #pragma unroll
    for (int off = 1; off < 64; off <<= 1) s += __shfl_xor(s, off);
    if (lane == 0) csq[c] = s;
}

// One wave = 32 rows (two 16-row m-tiles): each B-fragment feeds 2 MFMAs.
// Loads software-pipelined one blk ahead; epilogue VALU hides load latency.
__global__ __launch_bounds__(256, 2) void cluster_kernel(
        const float* __restrict__ x, const short* __restrict__ Cb,
        const short* __restrict__ CT, const float* __restrict__ csq,
        float* __restrict__ out) {
    __shared__ __align__(16) short Plds[4][32 * PSTR];
    const int wave = threadIdx.x >> 6;
    const int lane = threadIdx.x & 63;
    const int q = lane >> 4;
    const int lr = lane & 15;
    const int row0 = blockIdx.x * 128 + wave * 32;

    // A fragments: A[m=lane&15][k=(lane>>4)*8+j], k-step 32. Two row-tiles.
    v8s Ax[2][4];
    float xsq_r[2][4];
    #pragma unroll
    for (int t = 0; t < 2; ++t) {
        float xs = 0.f;
        const float* xrow = x + (size_t)(row0 + t * 16 + lr) * F_;
        #pragma unroll
        for (int ks = 0; ks < 4; ++ks) {
            const float4* p = (const float4*)(xrow + ks * 32 + q * 8);
            float4 a = p[0], b = p[1];
            float vv[8] = {a.x, a.y, a.z, a.w, b.x, b.y, b.z, b.w};
            v8s fr;
            #pragma unroll
            for (int j = 0; j < 8; ++j) {
                short bb = f2bf(vv[j]);
                fr[j] = bb;
                float r = bf2f(bb);
                xs += r * r;           // ||x~||^2 from bf16-rounded values
            }
            Ax[t][ks] = fr;
        }
        xs += __shfl_xor(xs, 16);
        xs += __shfl_xor(xs, 32);
        #pragma unroll
        for (int r = 0; r < 4; ++r) xsq_r[t][r] = __shfl(xs, q * 4 + r);
    }

    short* Pl = Plds[wave];
    v4f Of[2][8];
    #pragma unroll
    for (int t = 0; t < 2; ++t)
        #pragma unroll
        for (int i = 0; i < 8; ++i) Of[t][i] = (v4f){0.f, 0.f, 0.f, 0.f};
    float lpart[2][4] = {{0.f, 0.f, 0.f, 0.f}, {0.f, 0.f, 0.f, 0.f}};

    for (int kc = 0; kc < 4; ++kc) {
        // Prefetch cluster norms for this 128-chunk (per-lane: col = lr).
        float cq8[8];
        #pragma unroll
        for (int blk = 0; blk < 8; ++blk) cq8[blk] = csq[kc * 128 + blk * 16 + lr];

        // ---- stage 1: scores, pipelined one blk ahead ----
        const short* cb_base = Cb + (size_t)(kc * 128 + lr) * F_ + q * 8;
        v8s bcur[4], bnxt[4];
        #pragma unroll
        for (int ks = 0; ks < 4; ++ks) bcur[ks] = *(const v8s*)(cb_base + ks * 32);
        #pragma unroll
        for (int blk = 0; blk < 8; ++blk) {
            if (blk < 7) {
                const short* nb = cb_base + (size_t)(blk + 1) * 16 * F_;
                #pragma unroll
                for (int ks = 0; ks < 4; ++ks) bnxt[ks] = *(const v8s*)(nb + ks * 32);
            }
            v4f acc0 = (v4f){0.f, 0.f, 0.f, 0.f};
            v4f acc1 = (v4f){0.f, 0.f, 0.f, 0.f};
            #pragma unroll
            for (int ks = 0; ks < 4; ++ks) {
                acc0 = __builtin_amdgcn_mfma_f32_16x16x32_bf16(Ax[0][ks], bcur[ks], acc0, 0, 0, 0);
                acc1 = __builtin_amdgcn_mfma_f32_16x16x32_bf16(Ax[1][ks], bcur[ks], acc1, 0, 0, 0);
            }
            // C/D layout: col=lane&15 (cluster), row=(lane>>4)*4+reg (x-row)
            #pragma unroll
            for (int t = 0; t < 2; ++t) {
                #pragma unroll
                for (int r = 0; r < 4; ++r) {
                    float a = (t == 0) ? acc0[r] : acc1[r];
                    float d2 = xsq_r[t][r] + cq8[blk] - 2.0f * a;
                    float d = __builtin_amdgcn_sqrtf(fmaxf(d2, 0.f));
                    float pp = __expf(-d);
                    short pb = f2bf(pp);
                    lpart[t][r] += bf2f(pb);   // denom from SAME rounded p
                    Pl[(t * 16 + q * 4 + r) * PSTR + blk * 16 + lr] = pb;
                }
            }
            #pragma unroll
            for (int ks = 0; ks < 4; ++ks) bcur[ks] = bnxt[ks];
        }

        // ---- stage 2: O += P * C_chunk, CT frags pipelined one fblk ahead ----
        const short* ct_base = CT + (size_t)lr * K_ + kc * 128 + q * 8;
        #pragma unroll
        for (int ks2 = 0; ks2 < 4; ++ks2) {
            v8s pf0 = *(const v8s*)(Pl + lr * PSTR + ks2 * 32 + q * 8);
            v8s pf1 = *(const v8s*)(Pl + (16 + lr) * PSTR + ks2 * 32 + q * 8);
            v8s ccur = *(const v8s*)(ct_base + ks2 * 32);
            #pragma unroll
            for (int fblk = 0; fblk < 8; ++fblk) {
                v8s cnxt;
                if (fblk < 7)
                    cnxt = *(const v8s*)(ct_base + (size_t)(fblk + 1) * 16 * K_ + ks2 * 32);
                Of[0][fblk] = __builtin_amdgcn_mfma_f32_16x16x32_bf16(pf0, ccur, Of[0][fblk], 0, 0, 0);
                Of[1][fblk] = __builtin_amdgcn_mfma_f32_16x16x32_bf16(pf1, ccur, Of[1][fblk], 0, 0, 0);
                ccur = cnxt;
            }
        }
    }

    // Row softmax denominators: lpart[t][r] holds cols {lr + 16*blk}; reduce over lr.
    #pragma unroll
    for (int t = 0; t < 2; ++t) {
        #pragma unroll
        for (int r = 0; r < 4; ++r) {
            float s = lpart[t][r];
            s += __shfl_xor(s, 1);
            s += __shfl_xor(s, 2);
            s += __shfl_xor(s, 4);
            s += __shfl_xor(s, 8);
            lpart[t][r] = 1.0f / s;
        }
    }
    #pragma unroll
    for (int t = 0; t < 2; ++t) {
        #pragma unroll
        for (int fblk = 0; fblk < 8; ++fblk) {
            #pragma unroll
            for (int r = 0; r < 4; ++r) {
                const int row = row0 + t * 16 + q * 4 + r;
                out[(size_t)row * F_ + fblk * 16 + lr] = Of[t][fblk][r] * lpart[t][r];
            }
        }
    }
}

extern "C" void kernel_launch(void* const* d_in, const int* in_sizes, int n_in,
                              void* d_out, int out_size, void* d_ws, size_t ws_size,
                              hipStream_t stream) {
    const float* x       = (const float*)d_in[0];   // [8,8192,128] fp32
    const float* centers = (const float*)d_in[1];   // [512,128] fp32
    float* out = (float*)d_out;                     // [8,8192,128] fp32
    char* ws = (char*)d_ws;
    short* Cb  = (short*)ws;                 // 512*128*2  = 131072 B
    short* CT  = (short*)(ws + 131072);      // 128*512*2  = 131072 B
    float* csq = (float*)(ws + 262144);      // 512*4      = 2048 B
    prep_kernel<<<K_ / 4, 256, 0, stream>>>(centers, Cb, CT, csq);
    cluster_kernel<<<M_ / 128, 256, 0, stream>>>(x, Cb, CT, csq, out);
}

// Round 3
// 108.037 us; speedup vs baseline: 2.1523x; 1.3284x over previous
//
#include <hip/hip_runtime.h>
#include <hip/hip_bf16.h>

typedef short v8s __attribute__((ext_vector_type(8)));
typedef float v4f __attribute__((ext_vector_type(4)));

#define F_ 128
#define K_ 512
#define M_ 65536
#define PS 40   // P slab row stride in shorts (80 B = 5*16B: b128-aligned, conflict-free)

typedef __attribute__((address_space(1))) const char gch;
typedef __attribute__((address_space(3))) char lch;

__device__ __forceinline__ short f2bf(float f) {
    union { float f; unsigned u; } v; v.f = f;
    unsigned u = v.u;
    u = (u + 0x7FFFu + ((u >> 16) & 1u)) >> 16;  // RNE
    return (short)u;
}
__device__ __forceinline__ float bf2f(short s) {
    union { float f; unsigned u; } v;
    v.u = ((unsigned)(unsigned short)s) << 16;
    return v.f;
}

// One wave per cluster: bf16 convert (both layouts) + squared norm of rounded values.
__global__ void prep_kernel(const float* __restrict__ centers,
                            short* __restrict__ Cb, short* __restrict__ CT,
                            float* __restrict__ csq) {
    const int wave = threadIdx.x >> 6;
    const int lane = threadIdx.x & 63;
    const int c = blockIdx.x * 4 + wave;
    float s = 0.f;
    #pragma unroll
    for (int h = 0; h < 2; ++h) {
        const int f = h * 64 + lane;
        float v = centers[c * F_ + f];
        short b = f2bf(v);
        Cb[c * F_ + f] = b;        // [cluster][f]
        CT[f * K_ + c] = b;        // [f][cluster]
        float vb = bf2f(b);
        s += vb * vb;
    }
    #pragma unroll
    for (int off = 1; off < 64; off <<= 1) s += __shfl_xor(s, off);
    if (lane == 0) csq[c] = s;
}

// Stage one 64-cluster Cb chunk (16 KB = 1024 granules of 16B) into LDS.
// XOR swizzle: dest granule D holds global granule (D&~15)|((D&15)^((D>>4)&15)),
// so column-fragment reads (fixed granule slot, varying cluster) are 2-way free.
__device__ __forceinline__ void stage_cb(const short* Cb, short* dst,
                                         int c0, int wave, int lane) {
    #pragma unroll
    for (int call = 0; call < 4; ++call) {
        const int D  = wave * 256 + call * 64 + lane;
        const int c  = D >> 4;
        const int gs = (D & 15) ^ (c & 15);
        const char* src = (const char*)Cb + (size_t)(c0 + c) * 256 + gs * 16;
        __builtin_amdgcn_global_load_lds((gch*)src,
            (lch*)(dst + (size_t)(wave * 256 + call * 64) * 8), 16, 0, 0);
    }
}
// Stage one CT chunk [128 f][64 c] (16 KB, 8 granules per f-row), same idea mod 8.
__device__ __forceinline__ void stage_ct(const short* CT, short* dst,
                                         int c0, int wave, int lane) {
    #pragma unroll
    for (int call = 0; call < 4; ++call) {
        const int D  = wave * 256 + call * 64 + lane;
        const int f  = D >> 3;
        const int gs = (D & 7) ^ (f & 7);
        const char* src = (const char*)CT + (size_t)f * 1024 + (size_t)c0 * 2 + gs * 16;
        __builtin_amdgcn_global_load_lds((gch*)src,
            (lch*)(dst + (size_t)(wave * 256 + call * 64) * 8), 16, 0, 0);
    }
}

__global__ __launch_bounds__(256, 2) void cluster_kernel(
        const float* __restrict__ x, const short* __restrict__ Cb,
        const short* __restrict__ CT, const float* __restrict__ csq,
        float* __restrict__ out) {
    __shared__ __align__(16) short CbS[2][64 * F_];   // 2 x 16 KB, double-buffered
    __shared__ __align__(16) short CTS[F_ * 64];      // 16 KB, single-buffered
    __shared__ __align__(16) short Pl[4][32 * PS];    // per-wave P slab (32 rows x 32 cols)
    const int wave = threadIdx.x >> 6;
    const int lane = threadIdx.x & 63;
    const int q = lane >> 4;
    const int lr = lane & 15;
    const int row0 = blockIdx.x * 128 + wave * 32;

    // ---- x -> bf16 A-fragments (2 row-tiles) + bf16-consistent row norms ----
    v8s Ax[2][4];
    float xsq_r[2][4];
    #pragma unroll
    for (int t = 0; t < 2; ++t) {
        float xs = 0.f;
        const float* xrow = x + (size_t)(row0 + t * 16 + lr) * F_;
        #pragma unroll
        for (int ks = 0; ks < 4; ++ks) {
            const float4* p = (const float4*)(xrow + ks * 32 + q * 8);
            float4 a = p[0], b = p[1];
            float vv[8] = {a.x, a.y, a.z, a.w, b.x, b.y, b.z, b.w};
            v8s fr;
            #pragma unroll
            for (int j = 0; j < 8; ++j) {
                short bb = f2bf(vv[j]);
                fr[j] = bb;
                float r = bf2f(bb);
                xs += r * r;
            }
            Ax[t][ks] = fr;
        }
        xs += __shfl_xor(xs, 16);
        xs += __shfl_xor(xs, 32);
        #pragma unroll
        for (int r = 0; r < 4; ++r) xsq_r[t][r] = __shfl(xs, q * 4 + r);
    }

    short* Pw = Pl[wave];
    v4f Of[2][8];
    #pragma unroll
    for (int t = 0; t < 2; ++t)
        #pragma unroll
        for (int i = 0; i < 8; ++i) Of[t][i] = (v4f){0.f, 0.f, 0.f, 0.f};
    float lden[2][4] = {{0.f, 0.f, 0.f, 0.f}, {0.f, 0.f, 0.f, 0.f}};

    // Preload Cb chunk 0 (order staggered per block; accumulation is order-invariant).
    const int ord0 = blockIdx.x & 7;
    stage_cb(Cb, CbS[0], ord0 * 64, wave, lane);
    asm volatile("s_waitcnt vmcnt(0)" ::: "memory");
    __syncthreads();

    #pragma unroll 2
    for (int i = 0; i < 8; ++i) {
        const int ci  = (i + blockIdx.x) & 7;    // this chunk
        const int c0c = ci * 64;
        const int buf = i & 1;
        // CT(this chunk): staged now, needed first at slab-0 stage-2 (after mid barrier).
        stage_ct(CT, CTS, c0c, wave, lane);

        float cq4[4];
        #pragma unroll
        for (int b = 0; b < 4; ++b) cq4[b] = csq[c0c + b * 16 + lr];

        #pragma unroll
        for (int s = 0; s < 2; ++s) {            // two 32-cluster slabs per chunk
            // ---- stage 1: scores for this slab (2 blks of 16 clusters) ----
            #pragma unroll
            for (int b2 = 0; b2 < 2; ++b2) {
                const int blk = s * 2 + b2;
                v8s bf[4];
                #pragma unroll
                for (int ks = 0; ks < 4; ++ks) {
                    const int g = (blk * 16 + lr) * 16 + ((ks * 4 + q) ^ lr);
                    bf[ks] = *(const v8s*)&CbS[buf][g * 8];
                }
                v4f a0 = (v4f){0.f, 0.f, 0.f, 0.f};
                v4f a1 = (v4f){0.f, 0.f, 0.f, 0.f};
                #pragma unroll
                for (int ks = 0; ks < 4; ++ks) {
                    a0 = __builtin_amdgcn_mfma_f32_16x16x32_bf16(Ax[0][ks], bf[ks], a0, 0, 0, 0);
                    a1 = __builtin_amdgcn_mfma_f32_16x16x32_bf16(Ax[1][ks], bf[ks], a1, 0, 0, 0);
                }
                // C/D layout: col=lr (cluster), row=q*4+r. Pairs through v_cvt_pk_bf16_f32.
                #pragma unroll
                for (int t = 0; t < 2; ++t) {
                    #pragma unroll
                    for (int rp = 0; rp < 2; ++rp) {
                        const int r0i = rp * 2;
                        float a_0 = (t == 0) ? a0[r0i]     : a1[r0i];
                        float a_1 = (t == 0) ? a0[r0i + 1] : a1[r0i + 1];
                        float d20 = fmaxf(xsq_r[t][r0i]     + cq4[blk] - 2.0f * a_0, 0.f);
                        float d21 = fmaxf(xsq_r[t][r0i + 1] + cq4[blk] - 2.0f * a_1, 0.f);
                        float p0 = __expf(-__builtin_amdgcn_sqrtf(d20));
                        float p1 = __expf(-__builtin_amdgcn_sqrtf(d21));
                        union { __hip_bfloat162 h; unsigned u; } cv;
                        cv.h = __float22bfloat162_rn(make_float2(p0, p1));
                        const unsigned u = cv.u;
                        lden[t][r0i]     += __uint_as_float(u << 16);        // bf2f(lo)
                        lden[t][r0i + 1] += __uint_as_float(u & 0xffff0000); // bf2f(hi)
                        const int rowb = (t * 16 + q * 4 + r0i) * PS + b2 * 16 + lr;
                        Pw[rowb]      = (short)(u & 0xffff);
                        Pw[rowb + PS] = (short)(u >> 16);
                    }
                }
            }
            if (s == 0) {
                // Publish CTS to all waves; then start Cb(next) into the other buffer
                // (safe: buf^1 was last read before the END barrier of chunk i-1).
                asm volatile("s_waitcnt vmcnt(0)" ::: "memory");
                __syncthreads();
                if (i < 7) stage_cb(Cb, CbS[buf ^ 1], ((i + 1 + blockIdx.x) & 7) * 64, wave, lane);
            }
            // ---- stage 2: O += P_slab * C_slab (A=P from LDS, B=CT from LDS) ----
            v8s pf0 = *(const v8s*)&Pw[lr * PS + q * 8];
            v8s pf1 = *(const v8s*)&Pw[(16 + lr) * PS + q * 8];
            #pragma unroll
            for (int fblk = 0; fblk < 8; ++fblk) {
                const int f = fblk * 16 + lr;
                const int g = f * 8 + ((s * 4 + q) ^ (lr & 7));
                v8s cf = *(const v8s*)&CTS[g * 8];
                Of[0][fblk] = __builtin_amdgcn_mfma_f32_16x16x32_bf16(pf0, cf, Of[0][fblk], 0, 0, 0);
                Of[1][fblk] = __builtin_amdgcn_mfma_f32_16x16x32_bf16(pf1, cf, Of[1][fblk], 0, 0, 0);
            }
        }
        // END barrier: Cb(next) staged + all waves done with CTS/CbS[buf].
        asm volatile("s_waitcnt vmcnt(0)" ::: "memory");
        __syncthreads();
    }

    // Softmax denominators: lden[t][r] holds cols {lr + 16*blk}; reduce over lr.
    #pragma unroll
    for (int t = 0; t < 2; ++t) {
        #pragma unroll
        for (int r = 0; r < 4; ++r) {
            float sv = lden[t][r];
            sv += __shfl_xor(sv, 1);
            sv += __shfl_xor(sv, 2);
            sv += __shfl_xor(sv, 4);
            sv += __shfl_xor(sv, 8);
            lden[t][r] = 1.0f / sv;
        }
    }
    #pragma unroll
    for (int t = 0; t < 2; ++t) {
        #pragma unroll
        for (int fblk = 0; fblk < 8; ++fblk) {
            #pragma unroll
            for (int r = 0; r < 4; ++r) {
                const int row = row0 + t * 16 + q * 4 + r;
                out[(size_t)row * F_ + fblk * 16 + lr] = Of[t][fblk][r] * lden[t][r];
            }
        }
    }
}

extern "C" void kernel_launch(void* const* d_in, const int* in_sizes, int n_in,
                              void* d_out, int out_size, void* d_ws, size_t ws_size,
                              hipStream_t stream) {
    const float* x       = (const float*)d_in[0];   // [8,8192,128] fp32
    const float* centers = (const float*)d_in[1];   // [512,128] fp32
    float* out = (float*)d_out;                     // [8,8192,128] fp32
    char* ws = (char*)d_ws;
    short* Cb  = (short*)ws;                 // 512*128*2  = 131072 B
    short* CT  = (short*)(ws + 131072);      // 128*512*2  = 131072 B
    float* csq = (float*)(ws + 262144);      // 512*4      = 2048 B
    prep_kernel<<<K_ / 4, 256, 0, stream>>>(centers, Cb, CT, csq);
    cluster_kernel<<<M_ / 128, 256, 0, stream>>>(x, Cb, CT, csq, out);
}

// Round 4
// 104.415 us; speedup vs baseline: 2.2269x; 1.0347x over previous
//
#include <hip/hip_runtime.h>
#include <hip/hip_bf16.h>

typedef short v8s __attribute__((ext_vector_type(8)));
typedef float v16f __attribute__((ext_vector_type(16)));
typedef unsigned v2u __attribute__((ext_vector_type(2)));

#define F_ 128
#define K_ 512
#define M_ 65536
#define CH_SH 17408   // shorts per chunk table: Cb' 9216 (64c x 144f) + CT' 8192 (64c x 128f)
#define CB_OFF 9216

typedef __attribute__((address_space(1))) const char gch;
typedef __attribute__((address_space(3))) char lch;

__device__ __forceinline__ short f2bf(float f) {
    union { float f; unsigned u; } v; v.f = f;
    unsigned u = v.u;
    u = (u + 0x7FFFu + ((u >> 16) & 1u)) >> 16;  // RNE
    return (short)u;
}
__device__ __forceinline__ float bf2f(short s) {
    union { float f; unsigned u; } v;
    v.u = ((unsigned)(unsigned short)s) << 16;
    return v.f;
}

#if __has_builtin(__builtin_amdgcn_permlane32_swap)
#define HAVE_PLS 1
#endif

// (a,b) -> (a.lo||b.lo, a.hi||b.hi): the half-wave exchange for C->A layout.
__device__ __forceinline__ void pswap(unsigned &a, unsigned &b, int lane) {
#ifdef HAVE_PLS
    v2u r = __builtin_amdgcn_permlane32_swap(a, b, false, false);
    a = (unsigned)r.x; b = (unsigned)r.y;
#else
    unsigned sa = (unsigned)__shfl_xor((int)a, 32);
    unsigned sb = (unsigned)__shfl_xor((int)b, 32);
    if (lane & 32) a = sb; else b = sa;
#endif
}

// Build combined per-chunk tables in fragment-granule order.
// Cb' granule (ks,h,c64): A-frag bytes for stage-1 (m=cluster, k=f'), f'=ks*16+8h+j.
//   f'=128..143 augmentation: j0=-csq/2 hi, j1=lo (B side = 1), j2=1.0 (B side = -xsq/2 limbs).
// CT' granule (kap,h,f): B-frag bytes for stage-2 (k=cluster, n=f).
__global__ void prep_kernel(const float* __restrict__ centers, short* __restrict__ G) {
    const int c = blockIdx.x;     // 512 clusters
    const int f = threadIdx.x;    // 128 features
    const int ch = c >> 6, c64 = c & 63;
    const size_t base = (size_t)ch * CH_SH;
    float v = centers[c * F_ + f];
    short b = f2bf(v);
    float vb = bf2f(b);
    { const int ks = f >> 4, h = (f >> 3) & 1, j = f & 7;
      G[base + (size_t)((ks * 2 + h) * 64 + c64) * 8 + j] = b; }
    { const int kap = c64 >> 4, hh = (c64 >> 3) & 1, jj = c64 & 7;
      G[base + CB_OFF + (size_t)((kap * 2 + hh) * F_ + f) * 8 + jj] = b; }
    float s = vb * vb;
    #pragma unroll
    for (int off = 1; off < 64; off <<= 1) s += __shfl_xor(s, off);
    __shared__ float part[2];
    if ((f & 63) == 0) part[f >> 6] = s;
    __syncthreads();
    if (f < 16) {
        const float csq = part[0] + part[1];
        const float chv = -0.5f * csq;
        const short vh = f2bf(chv);
        const short vl = f2bf(chv - bf2f(vh));
        const short val = (f == 0) ? vh : (f == 1) ? vl : (f == 2) ? (short)0x3F80 : (short)0;
        const int h2 = f >> 3, j2 = f & 7;
        G[base + (size_t)((16 + h2) * 64 + c64) * 8 + j2] = val;
    }
}

// Linear 34 KB chunk copy via async DMA (dst = wave-uniform base + lane*16).
__device__ __forceinline__ void stage_chunk(const short* __restrict__ G, short* dst,
                                            int ch, int wave, int lane) {
    const char* src = (const char*)(G + (size_t)ch * CH_SH);
    lch* d = (lch*)dst;
    #pragma unroll
    for (int t = 0; t < 8; ++t) {
        const int g = t * 256 + wave * 64 + lane;
        __builtin_amdgcn_global_load_lds((gch*)(src + (size_t)g * 16),
                                         d + (size_t)(t * 256 + wave * 64) * 16, 16, 0, 0);
    }
    if (wave < 2) {
        const int g = 2048 + wave * 64 + lane;
        __builtin_amdgcn_global_load_lds((gch*)(src + (size_t)g * 16),
                                         d + (size_t)(2048 + wave * 64) * 16, 16, 0, 0);
    }
}

// One wave = 32 rows. Stage-1: S^T tiles (A=centers m-dim, B=x n-dim) via 32x32x16;
// d^2 = -2*acc (norms folded into K-slots 128..131). P transposed to A-layout with
// v_permlane32_swap (no LDS). Stage-2: O = P * C (B=CT' from LDS).
__global__ __launch_bounds__(256, 2) void cluster_kernel(
        const float* __restrict__ x, const short* __restrict__ G,
        float* __restrict__ out) {
    __shared__ __align__(16) short SB[2][CH_SH];   // 2 x 34 KB (Cb' + CT'), double-buffered
    const int tid = threadIdx.x;
    const int wave = tid >> 6, lane = tid & 63;
    const int h = lane >> 5, c32 = lane & 31;
    const int row0 = blockIdx.x * 128 + wave * 32;

    // x -> stage-1 B-fragments: B[k=f][n=row], lane: row=c32, f=ks*16+8h+j.
    v8s Bx[9];
    float xs = 0.f;
    const float* xr = x + (size_t)(row0 + c32) * F_;
    #pragma unroll
    for (int ks = 0; ks < 8; ++ks) {
        const float4* p = (const float4*)(xr + ks * 16 + h * 8);
        float4 a = p[0], b = p[1];
        float vv[8] = {a.x, a.y, a.z, a.w, b.x, b.y, b.z, b.w};
        v8s fr;
        #pragma unroll
        for (int j = 0; j < 8; ++j) {
            short bb = f2bf(vv[j]);
            fr[j] = bb;
            float r = bf2f(bb);
            xs += r * r;        // ||x~||^2 of bf16-rounded values
        }
        Bx[ks] = fr;
    }
    xs += __shfl_xor(xs, 32);   // combine the two f-halves of this row
    {
        const float xh = -0.5f * xs;
        const short sxh = f2bf(xh);
        const short sxl = f2bf(xh - bf2f(sxh));
        v8s e = (v8s){0, 0, 0, 0, 0, 0, 0, 0};
        if (h == 0) { e[0] = (short)0x3F80; e[1] = (short)0x3F80; e[2] = sxh; e[3] = sxl; }
        Bx[8] = e;              // k=128,129: 1.0 (x csq limbs); 130,131: -xsq/2 limbs (x 1.0)
    }

    v16f Of[4];
    #pragma unroll
    for (int ft = 0; ft < 4; ++ft)
        #pragma unroll
        for (int e2 = 0; e2 < 16; ++e2) Of[ft][e2] = 0.f;
    float lden = 0.f;

    stage_chunk(G, SB[0], blockIdx.x & 7, wave, lane);
    asm volatile("s_waitcnt vmcnt(0)" ::: "memory");
    __syncthreads();

    #pragma unroll 2
    for (int i = 0; i < 8; ++i) {
        const short* CbS = SB[i & 1];
        const short* CTS = CbS + CB_OFF;
        if (i < 7) stage_chunk(G, SB[(i + 1) & 1], (i + 1 + blockIdx.x) & 7, wave, lane);

        #pragma unroll
        for (int ct = 0; ct < 2; ++ct) {         // two 32-cluster m-tiles per chunk
            v16f acc;
            #pragma unroll
            for (int e2 = 0; e2 < 16; ++e2) acc[e2] = 0.f;
            #pragma unroll
            for (int ks = 0; ks < 9; ++ks) {
                v8s af = *(const v8s*)&CbS[(size_t)((ks * 2 + h) * 64 + ct * 32 + c32) * 8];
                acc = __builtin_amdgcn_mfma_f32_32x32x16_bf16(af, Bx[ks], acc, 0, 0, 0);
            }
            // Epilogue: 16 clusters of row c32. d^2 = -2*acc; p = exp(-d); pack pairs.
            unsigned U[8];
            #pragma unroll
            for (int t = 0; t < 8; ++t) {
                const float d20 = fmaxf(-2.0f * acc[2 * t], 0.f);
                const float d21 = fmaxf(-2.0f * acc[2 * t + 1], 0.f);
                const float p0 = __expf(-__builtin_amdgcn_sqrtf(d20));
                const float p1 = __expf(-__builtin_amdgcn_sqrtf(d21));
                union { __hip_bfloat162 hh; unsigned u; } cv;
                cv.hh = __float22bfloat162_rn(make_float2(p0, p1));
                U[t] = cv.u;
                lden += __uint_as_float(cv.u << 16);        // denom from SAME rounded p
                lden += __uint_as_float(cv.u & 0xffff0000u);
            }
            // C-layout -> A-layout: 2 permlane32_swap per k-step, all in registers.
            #pragma unroll
            for (int kp = 0; kp < 2; ++kp) {
                unsigned s0 = U[4 * kp],     s2 = U[4 * kp + 2];
                unsigned s1 = U[4 * kp + 1], s3 = U[4 * kp + 3];
                pswap(s0, s2, lane);
                pswap(s1, s3, lane);
                union { v8s v; unsigned u[4]; } pf;
                pf.u[0] = s0; pf.u[1] = s1; pf.u[2] = s2; pf.u[3] = s3;
                const int kap = ct * 2 + kp;
                #pragma unroll
                for (int ft = 0; ft < 4; ++ft) {
                    v8s cf = *(const v8s*)&CTS[(size_t)((kap * 2 + h) * F_ + ft * 32 + c32) * 8];
                    Of[ft] = __builtin_amdgcn_mfma_f32_32x32x16_bf16(pf.v, cf, Of[ft], 0, 0, 0);
                }
            }
        }
        asm volatile("s_waitcnt vmcnt(0)" ::: "memory");
        __syncthreads();
    }

    // Denominator: per-lane sum covers all 512 clusters of row c32 (both halves).
    lden += __shfl_xor(lden, 32);
    const float inv = 1.0f / lden;
    float invr[16];
    #pragma unroll
    for (int r = 0; r < 16; ++r)
        invr[r] = __shfl(inv, (r & 3) + 8 * (r >> 2) + 4 * h);
    // Stage-2 D: row = (r&3)+8*(r>>2)+4h (x-row), col = c32 (feature within f-tile).
    #pragma unroll
    for (int ft = 0; ft < 4; ++ft)
        #pragma unroll
        for (int r = 0; r < 16; ++r) {
            const int xrow = (r & 3) + 8 * (r >> 2) + 4 * h;
            out[(size_t)(row0 + xrow) * F_ + ft * 32 + c32] = Of[ft][r] * invr[r];
        }
}

extern "C" void kernel_launch(void* const* d_in, const int* in_sizes, int n_in,
                              void* d_out, int out_size, void* d_ws, size_t ws_size,
                              hipStream_t stream) {
    const float* x       = (const float*)d_in[0];   // [8,8192,128] fp32
    const float* centers = (const float*)d_in[1];   // [512,128] fp32
    float* out = (float*)d_out;                     // [8,8192,128] fp32
    short* G = (short*)d_ws;                        // 8 chunks x 34816 B = 278528 B
    prep_kernel<<<K_, F_, 0, stream>>>(centers, G);
    cluster_kernel<<<M_ / 128, 256, 0, stream>>>(x, G, out);
}